// Round 13
// baseline (131.992 us; speedup 1.0000x reference)
//
#include <hip/hip_runtime.h>

// SYMMETRIC single-kernel: f(K_ij) = f(K_ji), so each unordered tile pair is
// computed ONCE (1 exp per pair instead of 2). v_exp_f32 is ~16-cy issue-
// blocking (evidence: K≈13us vs 7us @8cy model; occupancy-insensitivity
// r7/r11) => exp is ~70% of the kernel; halving it is the only lever left.
// Structure: 512 blocks x 16-row tiles; block b sweeps j-tiles at distance
// dt=(J-b)&511 in [0,256] (tournament schedule). dt in {0,256}: row-acc only
// (both partners sweep; no col needed). dt in [1,255]: row-acc + col-acc; col
// contributions stored to colpart[b][dt][16] (exact-coverage: every slot
// rewritten every launch -> ws poison-safe). Resident-grid ticket barrier
// (device-global counters, zero at module load, self-reset by last exiter),
// then in-kernel reduce: out_i = b2 + rowacc_i + sum_dt colpart[(b-dt)][dt][i].
// launch_bounds(512,4) forces VGPR<=128 -> 2 blocks/CU -> all 512 resident
// (barrier-safe). Stats recomputed per block in fixed order (identical c).

#define NN     8192
#define TPB    512
#define RB     16
#define NTILE  (NN / RB)        // 512
#define NWV    (TPB / 64)       // 8
#define NCHUNK 9                // dt = 32*m + (tid>>4), m=0..8 -> dt in [0,287]
#define DTW    (NCHUNK * 32)    // 288 dt slots stored per block

#if __has_builtin(__builtin_amdgcn_exp2f)
#define EXP2(x) __builtin_amdgcn_exp2f(x)
#else
#define EXP2(x) exp2f(x)
#endif

__device__ unsigned gC = 0, gC2 = 0;   // zeroed at module load; self-resetting

__device__ __forceinline__ float rfl(float x) {
    return __int_as_float(__builtin_amdgcn_readfirstlane(__float_as_int(x)));
}

__global__ __launch_bounds__(TPB, 4) void sym_kernel(
    const float2* __restrict__ XX, const float* __restrict__ W1,
    const float* __restrict__ b1, const float* __restrict__ W2,
    const float* __restrict__ b2, float* __restrict__ out,
    float* __restrict__ colpart)
{
    __shared__ float ls[NWV], lq[NWV];
    __shared__ float csh;
    __shared__ float wred[NWV][RB];
    __shared__ float cred[32][RB];

    int tid = threadIdx.x;
    int b   = blockIdx.x;
    float w00 = W1[0], w01 = W1[1], w10 = W1[2], w11 = W1[3];
    float b0 = b1[0], bb1 = b1[1];

    // --- stats (identical fixed order in every block -> identical c) ---
    const float4* XX4 = (const float4*)XX;
    float s = 0.f, q = 0.f;
#pragma unroll
    for (int ii = 0; ii < (NN / 2) / TPB; ii++) {
        float4 v = XX4[ii * TPB + tid];
        float y0 = fmaf(v.y, w01, fmaf(v.x, w00, b0));
        float y1 = fmaf(v.y, w11, fmaf(v.x, w10, bb1));
        float y2 = fmaf(v.w, w01, fmaf(v.z, w00, b0));
        float y3 = fmaf(v.w, w11, fmaf(v.z, w10, bb1));
        s += (y0 + y1) + (y2 + y3);
        q += fmaf(y0, y0, y1 * y1) + fmaf(y2, y2, y3 * y3);
    }
#pragma unroll
    for (int o = 32; o > 0; o >>= 1) {
        s += __shfl_xor(s, o, 64);
        q += __shfl_xor(q, o, 64);
    }
    int wv = tid >> 6, lane = tid & 63;
    if (lane == 0) { ls[wv] = s; lq[wv] = q; }
    __syncthreads();
    if (tid == 0) {
        float S = 0.f, Q = 0.f;
#pragma unroll
        for (int i = 0; i < NWV; i++) { S += ls[i]; Q += lq[i]; }
        float M = (float)(2 * NN);
        float var = (Q - S * S / M) / (M - 1.0f);   // ddof=1
        csh = 1.4426950408889634f / var;            // c = log2e / var
    }
    __syncthreads();
    float c = csh;

    // --- row coefficients (wave-uniform -> SGPR via readfirstlane) ---
    int rowBase = b * RB;
    float A0s[RB], A1s[RB], Bs[RB], Gs[RB], acc[RB];
    float m2c = -2.0f * c;
#pragma unroll
    for (int r = 0; r < RB; r++) {
        float2 x = XX[rowBase + r];
        float y0 = fmaf(x.y, w01, fmaf(x.x, w00, b0));
        float y1 = fmaf(x.y, w11, fmaf(x.x, w10, bb1));
        A0s[r] = rfl(m2c * y0);
        A1s[r] = rfl(m2c * y1);
        Bs[r]  = rfl(c * fmaf(y0, y0, y1 * y1));
        Gs[r]  = rfl(-0.34657359027997264f * W2[rowBase + r]);
        acc[r] = 0.f;
    }

    // --- triangular sweep: dt = 32m + (tid>>4), jj = tid&15 ---
    int dtg = tid >> 4, jj = tid & 15;
#pragma unroll
    for (int m = 0; m < NCHUNK; m++) {
        int dt = 32 * m + dtg;                     // 0..287
        int J  = (b + dt) & (NTILE - 1);
        int j  = J * RB + jj;
        float2 xj = XX[j];
        float wj  = W2[j];
        float y0 = fmaf(xj.y, w01, fmaf(xj.x, w00, b0));
        float y1 = fmaf(xj.y, w11, fmaf(xj.x, w10, bb1));
        float rj = fmaf(y0, y0, y1 * y1);
        float gw = -0.34657359027997264f * wj;
        float gweff = (dt <= 256) ? gw : 0.f;      // rowacc mask
        float colacc = 0.f;
#pragma unroll
        for (int r = 0; r < RB; r++) {
            float kc = fmaf(A0s[r], y0, fmaf(A1s[r], y1, fmaf(c, rj, Bs[r])));
            float u  = kc * EXP2(kc);              // 1 exp per unordered pair
            acc[r]   = fmaf(u, gweff, acc[r]);     // out_row += gw_j * u
            colacc   = fmaf(u, Gs[r], colacc);     // out_col += gw_r * u
        }
        float cmask = (dt >= 1 && dt <= 255) ? 1.f : 0.f;
        // colpart[b][dt][jj]; offset = b*DTW*RB + m*TPB + tid (coalesced)
        colpart[(size_t)b * (DTW * RB) + (size_t)m * TPB + tid] = colacc * cmask;
    }

    // --- rowacc reduce across 512 threads (overlaps other blocks' arrival) ---
#pragma unroll
    for (int r = 0; r < RB; r++) {
#pragma unroll
        for (int o = 1; o <= 32; o <<= 1)
            acc[r] += __shfl_xor(acc[r], o, 64);
    }
    if (lane == 0) {
#pragma unroll
        for (int r = 0; r < RB; r++) wred[wv][r] = acc[r];
    }
    __syncthreads();                    // drains colpart stores (vmcnt 0)

    // --- resident-grid barrier (ticket; counters self-reset each launch) ---
    if (tid == 0) {
        __threadfence();                // release: make colpart visible
        atomicAdd(&gC, 1u);
        while (__hip_atomic_load(&gC, __ATOMIC_ACQUIRE, __HIP_MEMORY_SCOPE_AGENT)
               < (unsigned)NTILE)
            __builtin_amdgcn_s_sleep(2);
    }
    __syncthreads();
    __threadfence();                    // acquire: see other XCDs' colpart

    // --- gather col contributions: out rows of tile b need colpart[(b-dt)][dt][il]
    float csum = 0.f;
#pragma unroll
    for (int k = 0; k < 8; k++) {
        int dt  = dtg + 32 * k;                          // 0..255 (0 holds 0)
        int src = (b + NTILE - dt) & (NTILE - 1);
        csum += colpart[(size_t)src * (DTW * RB) + (size_t)dt * RB + jj];
    }
    cred[dtg][jj] = csum;
    __syncthreads();
    if (tid < RB) {
        float sR = b2[0];
#pragma unroll
        for (int ww = 0; ww < NWV; ww++) sR += wred[ww][tid];
#pragma unroll
        for (int g = 0; g < 32; g++) sR += cred[g][tid];
        out[rowBase + tid] = sR;
    }

    // --- exit: last block resets counters for the next (graph) launch ---
    __syncthreads();
    if (tid == 0) {
        unsigned t2 = atomicAdd(&gC2, 1u);
        if (t2 == (unsigned)(NTILE - 1)) {
            __hip_atomic_store(&gC,  0u, __ATOMIC_RELAXED, __HIP_MEMORY_SCOPE_AGENT);
            __hip_atomic_store(&gC2, 0u, __ATOMIC_RELAXED, __HIP_MEMORY_SCOPE_AGENT);
        }
    }
}

extern "C" void kernel_launch(void* const* d_in, const int* in_sizes, int n_in,
                              void* d_out, int out_size, void* d_ws, size_t ws_size,
                              hipStream_t stream)
{
    const float* XX = (const float*)d_in[0];
    const float* W1 = (const float*)d_in[1];
    const float* b1 = (const float*)d_in[2];
    const float* W2 = (const float*)d_in[3];
    const float* b2 = (const float*)d_in[4];
    float* out = (float*)d_out;
    float* colpart = (float*)d_ws;     // 512*288*16 floats = 9.4 MB

    sym_kernel<<<NTILE, TPB, 0, stream>>>((const float2*)XX, W1, b1, W2, b2,
                                          out, colpart);
}

// Round 14
// 22.958 us; speedup vs baseline: 5.7492x; 5.7492x over previous
//
#include <hip/hip_runtime.h>

// TWO-KERNEL SYMMETRIC: f(K_ij)=f(K_ji) computed once per unordered pair
// (r12 proved the math: absmax 32; r12's in-kernel grid barrier cost 120us of
// stall -> replaced by a second kernel; stream order is the dependency).
// K1: block b (rows b*16..b*16+15) sweeps j-tiles J=(b+dt)&511, dt in [0,287]
//     (32 dt-lanes x 9 chunks). dt<=256: row contributions -> out=b2+rowacc.
//     dt in [1,255]: col contributions -> colpart[J][dt][jj] (dest-major so
//     K2 reads are dense; every read slot rewritten each launch: poison-safe).
// K2: block b sums colpart[b][0..255][jj] (contiguous 16KB) into out[b*16+jj].
// Stats recomputed per block in fixed order -> identical c -> deterministic.

#define NN     8192
#define TPB    512
#define RB     16
#define NTILE  (NN / RB)        // 512
#define NWV    (TPB / 64)       // 8
#define NCHUNK 9                // dt = 32*m + (tid>>4) in [0,287]
#define DTW    (NCHUNK * 32)    // 288 dt slots per tile

#if __has_builtin(__builtin_amdgcn_exp2f)
#define EXP2(x) __builtin_amdgcn_exp2f(x)
#else
#define EXP2(x) exp2f(x)
#endif

__device__ __forceinline__ float rfl(float x) {
    return __int_as_float(__builtin_amdgcn_readfirstlane(__float_as_int(x)));
}

__global__ __launch_bounds__(TPB) void sweep_kernel(
    const float2* __restrict__ XX, const float* __restrict__ W1,
    const float* __restrict__ b1, const float* __restrict__ W2,
    const float* __restrict__ b2, float* __restrict__ out,
    float* __restrict__ colpart)
{
    __shared__ float ls[NWV], lq[NWV];
    __shared__ float csh;
    __shared__ float wred[NWV][RB];

    int tid = threadIdx.x;
    int b   = blockIdx.x;
    float w00 = W1[0], w01 = W1[1], w10 = W1[2], w11 = W1[3];
    float b0 = b1[0], bb1 = b1[1];

    // --- stats (identical fixed order in every block -> identical c) ---
    const float4* XX4 = (const float4*)XX;
    float s = 0.f, q = 0.f;
#pragma unroll
    for (int ii = 0; ii < (NN / 2) / TPB; ii++) {
        float4 v = XX4[ii * TPB + tid];
        float y0 = fmaf(v.y, w01, fmaf(v.x, w00, b0));
        float y1 = fmaf(v.y, w11, fmaf(v.x, w10, bb1));
        float y2 = fmaf(v.w, w01, fmaf(v.z, w00, b0));
        float y3 = fmaf(v.w, w11, fmaf(v.z, w10, bb1));
        s += (y0 + y1) + (y2 + y3);
        q += fmaf(y0, y0, y1 * y1) + fmaf(y2, y2, y3 * y3);
    }
#pragma unroll
    for (int o = 32; o > 0; o >>= 1) {
        s += __shfl_xor(s, o, 64);
        q += __shfl_xor(q, o, 64);
    }
    int wv = tid >> 6, lane = tid & 63;
    if (lane == 0) { ls[wv] = s; lq[wv] = q; }
    __syncthreads();
    if (tid == 0) {
        float S = 0.f, Q = 0.f;
#pragma unroll
        for (int i = 0; i < NWV; i++) { S += ls[i]; Q += lq[i]; }
        float M = (float)(2 * NN);
        float var = (Q - S * S / M) / (M - 1.0f);   // ddof=1
        csh = 1.4426950408889634f / var;            // c = log2e / var
    }
    __syncthreads();
    float c = csh;

    // --- row coefficients (wave-uniform -> SGPR via readfirstlane) ---
    int rowBase = b * RB;
    float A0s[RB], A1s[RB], Bs[RB], Gs[RB], acc[RB];
    float m2c = -2.0f * c;
#pragma unroll
    for (int r = 0; r < RB; r++) {
        float2 x = XX[rowBase + r];
        float y0 = fmaf(x.y, w01, fmaf(x.x, w00, b0));
        float y1 = fmaf(x.y, w11, fmaf(x.x, w10, bb1));
        A0s[r] = rfl(m2c * y0);
        A1s[r] = rfl(m2c * y1);
        Bs[r]  = rfl(c * fmaf(y0, y0, y1 * y1));
        Gs[r]  = rfl(-0.34657359027997264f * W2[rowBase + r]);
        acc[r] = 0.f;
    }

    // --- triangular sweep: dt = 32m + (tid>>4), jj = tid&15 ---
    int dtg = tid >> 4, jj = tid & 15;
#pragma unroll
    for (int m = 0; m < NCHUNK; m++) {
        int dt = 32 * m + dtg;                     // 0..287
        int J  = (b + dt) & (NTILE - 1);
        int j  = J * RB + jj;
        float2 xj = XX[j];
        float wj  = W2[j];
        float y0 = fmaf(xj.y, w01, fmaf(xj.x, w00, b0));
        float y1 = fmaf(xj.y, w11, fmaf(xj.x, w10, bb1));
        float rj = fmaf(y0, y0, y1 * y1);
        float gw = -0.34657359027997264f * wj;
        float gweff = (dt <= 256) ? gw : 0.f;      // rowacc mask
        float colacc = 0.f;
#pragma unroll
        for (int r = 0; r < RB; r++) {
            float kc = fmaf(A0s[r], y0, fmaf(A1s[r], y1, fmaf(c, rj, Bs[r])));
            float u  = kc * EXP2(kc);              // 1 exp per unordered pair
            acc[r]   = fmaf(u, gweff, acc[r]);     // out_row += gw_j * u
            colacc   = fmaf(u, Gs[r], colacc);     // out_col += gw_r * u
        }
        float cmask = (dt >= 1 && dt <= 255) ? 1.f : 0.f;
        // dest-major: colpart[J][dt][jj] -> K2 reads are dense per tile
        colpart[(size_t)J * (DTW * RB) + (size_t)dt * RB + jj] = colacc * cmask;
    }

    // --- rowacc reduce; out = b2 + rowacc (K2 adds col part) ---
#pragma unroll
    for (int r = 0; r < RB; r++) {
#pragma unroll
        for (int o = 1; o <= 32; o <<= 1)
            acc[r] += __shfl_xor(acc[r], o, 64);
    }
    if (lane == 0) {
#pragma unroll
        for (int r = 0; r < RB; r++) wred[wv][r] = acc[r];
    }
    __syncthreads();
    if (tid < RB) {
        float sR = b2[0];
#pragma unroll
        for (int ww = 0; ww < NWV; ww++) sR += wred[ww][tid];
        out[rowBase + tid] = sR;
    }
}

__global__ __launch_bounds__(256) void gather_kernel(
    const float* __restrict__ colpart, float* __restrict__ out)
{
    int tid = threadIdx.x;
    int b   = blockIdx.x;
    float prev = 0.f;
    if (tid < RB) prev = out[b * RB + tid];        // issue early (hide latency)

    // flat f = k*256 + tid = dt*16 + jj, dt = 16k + (tid>>4), jj = tid&15
    float csum = 0.f;
#pragma unroll
    for (int k = 0; k < 16; k++)
        csum += colpart[(size_t)b * (DTW * RB) + k * 256 + tid];

    csum += __shfl_xor(csum, 16, 64);
    csum += __shfl_xor(csum, 32, 64);
    __shared__ float lds[4][RB];
    int wv = tid >> 6, l = tid & 63;
    if (l < RB) lds[wv][l] = csum;
    __syncthreads();
    if (tid < RB) {
        float t = prev;
#pragma unroll
        for (int w = 0; w < 4; w++) t += lds[w][tid];
        out[b * RB + tid] = t;
    }
}

extern "C" void kernel_launch(void* const* d_in, const int* in_sizes, int n_in,
                              void* d_out, int out_size, void* d_ws, size_t ws_size,
                              hipStream_t stream)
{
    const float* XX = (const float*)d_in[0];
    const float* W1 = (const float*)d_in[1];
    const float* b1 = (const float*)d_in[2];
    const float* W2 = (const float*)d_in[3];
    const float* b2 = (const float*)d_in[4];
    float* out = (float*)d_out;
    float* colpart = (float*)d_ws;     // 512*288*16 floats = 9.4 MB

    sweep_kernel<<<NTILE, TPB, 0, stream>>>((const float2*)XX, W1, b1, W2, b2,
                                            out, colpart);
    gather_kernel<<<NTILE, 256, 0, stream>>>(colpart, out);
}

// Round 15
// 20.348 us; speedup vs baseline: 6.4868x; 1.1283x over previous
//
#include <hip/hip_runtime.h>

// FINAL = round-7 kernel (best measured: 20.25us, absmax 32).
// Fused single kernel, no LDS tile (j-stream is L2-resident), RB=16 rows/block.
//   y = XX@W1^T + b1; standardize over all 2N elems (ddof=1) => only
//   c = log2e/var needed (mean cancels in pairwise differences).
//   kc = c*(r_i + r_j - 2 y_i.y_j) = log2e*K;  term = (-ln2/2*W2_j)*kc*2^kc.
// Inner per 2 pairs: 3 pk_fma + pk_mul + pk_fma + 2 v_exp_f32.
// Why this is the stopping point (measured decomposition):
//   total = C(harness ~5.3us) + L(launch ~3.5us) + K(kernel ~11.5us).
//   K is issue-bound: per 1024 pairs = 80 VALU-eq x 2cy + 16 exp x 16cy
//   = 416 cy -> floor 11.1us; we're within ~3%.
//   - v_exp_f32 = 16cy/wave-inst (fits r7/r11/r13 datapoints) = 62% of issue.
//   - symmetry halving needs cross-block comm: grid barrier +120us (r12),
//     2nd kernel +L+K2 > gain (r13). Poly-exp2 breaks even at best. pk-f32
//     is issue-neutral on gfx950 (no dual-fp32). MFMA kc (bf16x3) models -2us
//     for a high-risk rewrite.
// Every block recomputes stats in identical fixed order -> deterministic.

#define NN   8192
#define TPB  512
#define RB   16              // rows per block (all threads share these rows)
#define NH   (RB / 2)        // 8 v2f row-groups
#define JPT  (NN / TPB)      // 16 j per thread
#define NWV  (TPB / 64)      // 8 waves per block

typedef float v2f __attribute__((ext_vector_type(2)));

#if __has_builtin(__builtin_amdgcn_exp2f)
#define EXP2(x) __builtin_amdgcn_exp2f(x)
#else
#define EXP2(x) exp2f(x)
#endif

__global__ __launch_bounds__(TPB, 4) void fused_kernel(
    const float2* __restrict__ XX, const float* __restrict__ W1,
    const float* __restrict__ b1, const float* __restrict__ W2,
    const float* __restrict__ b2, float* __restrict__ out)
{
    __shared__ float ls[NWV], lq[NWV];
    __shared__ float csh;
    __shared__ float wred[NWV][RB];

    int tid = threadIdx.x;
    float w00 = W1[0], w01 = W1[1], w10 = W1[2], w11 = W1[3];
    float b0 = b1[0], bb1 = b1[1];

    // --- stats partial (identical order in every block -> identical c) ---
    const float4* XX4 = (const float4*)XX;
    float s = 0.f, q = 0.f;
#pragma unroll
    for (int ii = 0; ii < (NN / 2) / TPB; ii++) {      // 8 unrolled iters
        float4 v = XX4[ii * TPB + tid];
        float y0 = fmaf(v.y, w01, fmaf(v.x, w00, b0));
        float y1 = fmaf(v.y, w11, fmaf(v.x, w10, bb1));
        float y2 = fmaf(v.w, w01, fmaf(v.z, w00, b0));
        float y3 = fmaf(v.w, w11, fmaf(v.z, w10, bb1));
        s += (y0 + y1) + (y2 + y3);
        q += fmaf(y0, y0, y1 * y1) + fmaf(y2, y2, y3 * y3);
    }
#pragma unroll
    for (int o = 32; o > 0; o >>= 1) {
        s += __shfl_xor(s, o, 64);
        q += __shfl_xor(q, o, 64);
    }
    int wv = tid >> 6;
    if ((tid & 63) == 0) { ls[wv] = s; lq[wv] = q; }
    __syncthreads();
    if (tid == 0) {
        float S = 0.f, Q = 0.f;
#pragma unroll
        for (int i = 0; i < NWV; i++) { S += ls[i]; Q += lq[i]; }
        float M = (float)(2 * NN);
        float var = (Q - S * S / M) / (M - 1.0f);   // ddof=1
        csh = 1.4426950408889634f / var;            // c = log2e / var
    }
    __syncthreads();
    float c = csh;

    // --- row registers: RB=16 rows per block, 8 v2f groups per thread ---
    int rowBase = blockIdx.x * RB;
    v2f A0p[NH], A1p[NH], Bp[NH], accp[NH];
    const v2f cp = {c, c};
    float m2c = -2.0f * c;
#pragma unroll
    for (int h = 0; h < NH; h++) {
        float2 xa = XX[rowBase + 2 * h];
        float2 xb = XX[rowBase + 2 * h + 1];
        float ya0 = fmaf(xa.y, w01, fmaf(xa.x, w00, b0));
        float ya1 = fmaf(xa.y, w11, fmaf(xa.x, w10, bb1));
        float yb0 = fmaf(xb.y, w01, fmaf(xb.x, w00, b0));
        float yb1 = fmaf(xb.y, w11, fmaf(xb.x, w10, bb1));
        A0p[h] = (v2f){m2c * ya0, m2c * yb0};
        A1p[h] = (v2f){m2c * ya1, m2c * yb1};
        Bp[h]  = (v2f){c * fmaf(ya0, ya0, ya1 * ya1), c * fmaf(yb0, yb0, yb1 * yb1)};
        accp[h] = (v2f){0.f, 0.f};
    }

    // --- main loop: j straight from global (L2-resident), no LDS, no barriers ---
#pragma unroll 4
    for (int k = 0; k < JPT; k++) {
        int j = k * TPB + tid;                 // lanes -> consecutive j: coalesced
        float2 xj = XX[j];
        float wj = W2[j];
        float y0 = fmaf(xj.y, w01, fmaf(xj.x, w00, b0));
        float y1 = fmaf(xj.y, w11, fmaf(xj.x, w10, bb1));
        float rj = fmaf(y0, y0, y1 * y1);
        float gw = -0.34657359027997264f * wj; // -(ln2)/2 * W2_j
        v2f qx = {y0, y0};
        v2f qy = {y1, y1};
        v2f qz = {rj, rj};
        v2f qw = {gw, gw};
#pragma unroll
        for (int h = 0; h < NH; h++) {
            v2f kc = __builtin_elementwise_fma(A0p[h], qx,
                     __builtin_elementwise_fma(A1p[h], qy,
                     __builtin_elementwise_fma(cp, qz, Bp[h])));
            v2f e;
            e.x = EXP2(kc.x);                  // v_exp_f32
            e.y = EXP2(kc.y);
            accp[h] = __builtin_elementwise_fma(qw * kc, e, accp[h]);
        }
    }

    // --- reduce: 512 threads all hold partials for the same 16 rows ---
#pragma unroll
    for (int h = 0; h < NH; h++) {
#pragma unroll
        for (int o = 1; o <= 32; o <<= 1) {
            accp[h].x += __shfl_xor(accp[h].x, o, 64);
            accp[h].y += __shfl_xor(accp[h].y, o, 64);
        }
    }
    if ((tid & 63) == 0) {
#pragma unroll
        for (int h = 0; h < NH; h++) {
            wred[wv][2 * h]     = accp[h].x;
            wred[wv][2 * h + 1] = accp[h].y;
        }
    }
    __syncthreads();
    if (tid < RB) {
        float sR = b2[0];
#pragma unroll
        for (int ww = 0; ww < NWV; ww++) sR += wred[ww][tid];
        out[rowBase + tid] = sR;
    }
}

extern "C" void kernel_launch(void* const* d_in, const int* in_sizes, int n_in,
                              void* d_out, int out_size, void* d_ws, size_t ws_size,
                              hipStream_t stream)
{
    const float* XX = (const float*)d_in[0];
    const float* W1 = (const float*)d_in[1];
    const float* b1 = (const float*)d_in[2];
    const float* W2 = (const float*)d_in[3];
    const float* b2 = (const float*)d_in[4];
    float* out = (float*)d_out;

    fused_kernel<<<NN / RB, TPB, 0, stream>>>((const float2*)XX, W1, b1, W2, b2, out);
}